// Round 13
// baseline (66.616 us; speedup 1.0000x reference)
//
#include <hip/hip_runtime.h>
#include <math.h>

#define DT 0.005f
#define NTHREADS 256
#define NBLOCKS 2048
#define NBUCKET 32
#define ELEMS_PER_BLOCK 1024
#define ROUNDS 4
#define NPREP 1024

typedef float    fvec4 __attribute__((ext_vector_type(4)));
typedef float    fvec2 __attribute__((ext_vector_type(2)));
typedef unsigned uvec4 __attribute__((ext_vector_type(4)));

__device__ __forceinline__ fvec4 ntload4f(const float* p) {
    return __builtin_nontemporal_load(reinterpret_cast<const fvec4*>(p));
}
__device__ __forceinline__ fvec2 ntload2f(const float* p) {
    return __builtin_nontemporal_load(reinterpret_cast<const fvec2*>(p));
}
__device__ __forceinline__ float ntloadf(const float* p) {
    return __builtin_nontemporal_load(p);
}
__device__ __forceinline__ int ntloadi(const int* p) {
    return __builtin_nontemporal_load(p);
}
__device__ __forceinline__ uvec4 ntload4u(const unsigned* p) {
    return __builtin_nontemporal_load(reinterpret_cast<const uvec4*>(p));
}

__device__ __forceinline__ void stream_compute(
    const float* __restrict__ quat, const float* __restrict__ tpos,
    const float* __restrict__ bias, const float* __restrict__ batchX,
    int i, int SF, int last_off,
    float gx, float gy, float gz, float half_dt2,
    float& cx, float& cy, float& cz)
{
    fvec4 q = ntload4f(quat + (size_t)i * 4);
    const float* tp = tpos + (size_t)i * 3;
    float tpx = ntloadf(tp + 0), tpy = ntloadf(tp + 1), tpz = ntloadf(tp + 2);
    const float* bp = bias + (size_t)i * 3;
    float bx = ntloadf(bp + 0), by = ntloadf(bp + 1), bz = ntloadf(bp + 2);
    const float* xb = batchX + (size_t)i * SF + last_off;
    fvec2 a01 = ntload2f(xb);
    float ax = a01.x - bx;
    float ay = a01.y - by;
    float az = ntloadf(xb + 2) - bz;

    float t0 = -(q.y * ax + q.z * ay + q.w * az);
    float t1 =   q.x * ax + q.z * az - q.w * ay;
    float t2 =   q.x * ay - q.y * az + q.w * ax;
    float t3 =   q.x * az + q.y * ay - q.z * ax;
    float rx = -t0 * q.y + t1 * q.x - t2 * q.w + t3 * q.z;
    float ry = -t0 * q.z + t1 * q.w + t2 * q.x - t3 * q.y;
    float rz = -t0 * q.w - t1 * q.z + t2 * q.y + t3 * q.x;

    cx = half_dt2 * (gx + rx) - tpx;
    cy = half_dt2 * (gy + ry) - tpy;
    cz = half_dt2 * (gz + rz) - tpz;
}

__device__ __forceinline__ float huber3(float dx, float dy, float dz) {
    float adx = fabsf(dx), ady = fabsf(dy), adz = fabsf(dz);
    float h = (adx < 1.f) ? 0.5f * dx * dx : adx - 0.5f;
    h += (ady < 1.f) ? 0.5f * dy * dy : ady - 0.5f;
    h += (adz < 1.f) ? 0.5f * dz * dz : adz - 0.5f;
    return h;
}

// ---------------- K1: bin blocks + prep blocks in one launch ----------------
// blocks [0, nseg): stream + deterministic 32-bucket multisplit
// blocks [nseg, nseg+NPREP): w4[n] = {pos_all[n]+DT*vel_all[n], pad}
__global__ __launch_bounds__(NTHREADS) void k1_bin_prep(
    const float* __restrict__ quat,
    const float* __restrict__ tpos,
    const float* __restrict__ bias,
    const float* __restrict__ batchX,
    const float* __restrict__ pos_all,
    const float* __restrict__ vel_all,
    const float* __restrict__ grav,
    const int*   __restrict__ indices,
    const int*   __restrict__ seq_len_p,
    int SF, int shift, int nseg, int N,
    uvec4* __restrict__ pairs,
    int*   __restrict__ dirs,
    float* __restrict__ w4)          // N*4 floats
{
    const int tid = threadIdx.x;

    if ((int)blockIdx.x >= nseg) {
        // ---------- prep path: pure streaming ----------
        const int pb = blockIdx.x - nseg;
        const int stride = NPREP * NTHREADS;
        for (int n = pb * NTHREADS + tid; n < N; n += stride) {
            const float* pp = pos_all + (size_t)n * 3;
            const float* vp = vel_all + (size_t)n * 3;
            fvec4 r;
            r.x = pp[0] + DT * vp[0];
            r.y = pp[1] + DT * vp[1];
            r.z = pp[2] + DT * vp[2];
            r.w = 0.f;
            *reinterpret_cast<fvec4*>(w4 + (size_t)n * 4) = r;
        }
        return;
    }

    // ---------- bin path ----------
    const int S = *seq_len_p;
    const int F = SF / S;
    const int last_off = (S - 1) * F;
    const float gx = grav[0], gy = grav[1], gz = grav[2];
    const float half_dt2 = 0.5f * DT * DT;

    __shared__ int   cnt[ROUNDS][4][NBUCKET];
    __shared__ int   offarr[ROUNDS][4][NBUCKET];
    __shared__ int   bstart[NBUCKET];
    __shared__ uvec4 stage[ELEMS_PER_BLOCK];

    const int wave = tid >> 6;
    const int lane = tid & 63;
    const unsigned long long ltmask = (1ull << lane) - 1ull;

    for (int k = tid; k < ROUNDS * 4 * NBUCKET; k += NTHREADS)
        ((int*)cnt)[k] = 0;
    __syncthreads();

    const int base = blockIdx.x * ELEMS_PER_BLOCK;

    int   idxv[ROUNDS], bckt[ROUNDS], rnk[ROUNDS];
    float cxv[ROUNDS], cyv[ROUNDS], czv[ROUNDS];

    #pragma unroll
    for (int r = 0; r < ROUNDS; ++r) {
        const int i = base + r * NTHREADS + tid;
        int idx = ntloadi(indices + i) - (S - 1);
        if (idx < 0) idx = 0;
        idxv[r] = idx;
        int b = idx >> shift; if (b > NBUCKET - 1) b = NBUCKET - 1;
        bckt[r] = b;

        unsigned long long mask = ~0ull;
        #pragma unroll
        for (int k = 0; k < 5; ++k) {
            unsigned long long bm = __ballot((b >> k) & 1);
            mask &= ((b >> k) & 1) ? bm : ~bm;
        }
        rnk[r] = __popcll(mask & ltmask);
        if (rnk[r] == 0) cnt[r][wave][b] = __popcll(mask);

        stream_compute(quat, tpos, bias, batchX, i, SF, last_off,
                       gx, gy, gz, half_dt2, cxv[r], cyv[r], czv[r]);
    }
    __syncthreads();

    if (tid < NBUCKET) {
        int b = tid, off = 0;
        #pragma unroll
        for (int r = 0; r < ROUNDS; ++r)
            #pragma unroll
            for (int w = 0; w < 4; ++w) {
                offarr[r][w][b] = off;
                off += cnt[r][w][b];
            }
        dirs[blockIdx.x * NBUCKET + b] = off;
        cnt[0][0][b] = off;
    }
    __syncthreads();
    if (tid == 0) {
        int s = 0;
        #pragma unroll
        for (int b = 0; b < NBUCKET; ++b) { bstart[b] = s; s += cnt[0][0][b]; }
    }
    __syncthreads();

    #pragma unroll
    for (int r = 0; r < ROUNDS; ++r) {
        int slot = bstart[bckt[r]] + offarr[r][wave][bckt[r]] + rnk[r];
        uvec4 v;
        v.x = (unsigned)idxv[r];
        v.y = __float_as_uint(cxv[r]);
        v.z = __float_as_uint(cyv[r]);
        v.w = __float_as_uint(czv[r]);
        stage[slot] = v;
    }
    __syncthreads();

    #pragma unroll
    for (int r = 0; r < ROUNDS; ++r)
        pairs[(size_t)base + r * NTHREADS + tid] = stage[r * NTHREADS + tid];
}

// ---------------- K2: XCD-sliced gather from padded w4 ----------------
__global__ __launch_bounds__(NTHREADS) void k2_gather_w(
    const float* __restrict__ w4,
    const uvec4* __restrict__ pairs,
    const int*   __restrict__ dirs,
    float* __restrict__ partials)
{
    const int r = blockIdx.x & 7;
    const int j = blockIdx.x >> 3;
    const int tid = threadIdx.x;

    __shared__ int dcnt[8][NBUCKET];
    __shared__ int segSrc[8];
    __shared__ int segCum[9];
    __shared__ float wsum[NTHREADS / 64];

    {
        int s = tid >> 5, bb = tid & (NBUCKET - 1);
        dcnt[s][bb] = dirs[(j * 8 + s) * NBUCKET + bb];
    }
    __syncthreads();

    float hsum = 0.f;

    for (int phase = 0; phase < NBUCKET / 8; ++phase) {
        const int b = r + 8 * phase;

        if (tid < 8) {
            int s = tid, st = 0;
            for (int bb = 0; bb < b; ++bb) st += dcnt[s][bb];
            segSrc[s] = (j * 8 + s) * ELEMS_PER_BLOCK + st;
            segCum[s] = dcnt[s][b];
        }
        __syncthreads();
        if (tid == 0) {
            int c = 0;
            #pragma unroll
            for (int s = 0; s < 8; ++s) { int l = segCum[s]; segCum[s] = c; c += l; }
            segCum[8] = c;
        }
        __syncthreads();

        const int tot = segCum[8];
        for (int m = tid; m < tot; m += NTHREADS) {
            int s = 0;
            #pragma unroll
            for (int k = 1; k < 8; ++k) s += (m >= segCum[k]);
            uvec4 pr = ntload4u(
                reinterpret_cast<const unsigned*>(pairs + segSrc[s] + (m - segCum[s])));
            int idx = (int)pr.x;
            fvec4 wv = *reinterpret_cast<const fvec4*>(w4 + (size_t)idx * 4);
            hsum += huber3(wv.x + __uint_as_float(pr.y),
                           wv.y + __uint_as_float(pr.z),
                           wv.z + __uint_as_float(pr.w));
        }
        __syncthreads();
    }

    for (int off = 32; off > 0; off >>= 1)
        hsum += __shfl_down(hsum, off);

    int lane = tid & 63, wid = tid >> 6;
    if (lane == 0) wsum[wid] = hsum;
    __syncthreads();
    if (tid == 0) {
        float s = 0.f;
        for (int w = 0; w < NTHREADS / 64; ++w) s += wsum[w];
        partials[blockIdx.x] = s;
    }
}

// ---------------- Fallback: proven round-5 single-pass ----------------
__global__ __launch_bounds__(NTHREADS) void pos_loss_partial(
    const float* __restrict__ quat,
    const float* __restrict__ tpos,
    const float* __restrict__ bias,
    const float* __restrict__ batchX,
    const float* __restrict__ pos_all,
    const float* __restrict__ vel_all,
    const float* __restrict__ grav,
    const int*   __restrict__ indices,
    const int*   __restrict__ seq_len_p,
    int B, int SF,
    float* __restrict__ partials)
{
    const int S = *seq_len_p;
    const int F = SF / S;
    const int last_off = (S - 1) * F;
    const float gx = grav[0], gy = grav[1], gz = grav[2];
    const float half_dt2 = 0.5f * DT * DT;

    float hsum = 0.f;

    for (int i = blockIdx.x * blockDim.x + threadIdx.x; i < B;
         i += gridDim.x * blockDim.x) {
        int idx = ntloadi(indices + i) - (S - 1);
        if (idx < 0) idx = 0;
        const float* pp = pos_all + (size_t)idx * 3;
        const float* vp = vel_all + (size_t)idx * 3;
        float p0x = pp[0], p0y = pp[1], p0z = pp[2];
        float v0x = vp[0], v0y = vp[1], v0z = vp[2];

        float cx, cy, cz;
        stream_compute(quat, tpos, bias, batchX, i, SF, last_off,
                       gx, gy, gz, half_dt2, cx, cy, cz);

        hsum += huber3(p0x + v0x * DT + cx,
                       p0y + v0y * DT + cy,
                       p0z + v0z * DT + cz);
    }

    for (int off = 32; off > 0; off >>= 1)
        hsum += __shfl_down(hsum, off);

    __shared__ float wsum[NTHREADS / 64];
    int lane = threadIdx.x & 63;
    int wid  = threadIdx.x >> 6;
    if (lane == 0) wsum[wid] = hsum;
    __syncthreads();
    if (threadIdx.x == 0) {
        float s = 0.f;
        for (int w = 0; w < NTHREADS / 64; ++w) s += wsum[w];
        partials[blockIdx.x] = s;
    }
}

__global__ __launch_bounds__(NTHREADS) void pos_loss_finish(
    const float* __restrict__ partials, int nb, float inv_cnt,
    float* __restrict__ out)
{
    float s = 0.f;
    for (int i = threadIdx.x; i < nb; i += NTHREADS) s += partials[i];
    for (int off = 32; off > 0; off >>= 1)
        s += __shfl_down(s, off);
    __shared__ float wsum[NTHREADS / 64];
    int lane = threadIdx.x & 63;
    int wid  = threadIdx.x >> 6;
    if (lane == 0) wsum[wid] = s;
    __syncthreads();
    if (threadIdx.x == 0) {
        float tot = 0.f;
        for (int w = 0; w < NTHREADS / 64; ++w) tot += wsum[w];
        out[0] = tot * inv_cnt;
    }
}

extern "C" void kernel_launch(void* const* d_in, const int* in_sizes, int n_in,
                              void* d_out, int out_size, void* d_ws, size_t ws_size,
                              hipStream_t stream) {
    const float* quat    = (const float*)d_in[0];
    const float* tpos    = (const float*)d_in[1];
    const float* bias    = (const float*)d_in[2];
    const float* batchX  = (const float*)d_in[3];
    const float* pos_all = (const float*)d_in[4];
    const float* vel_all = (const float*)d_in[5];
    const float* grav    = (const float*)d_in[6];
    const int*   indices = (const int*)d_in[7];
    const int*   seqlen  = (const int*)d_in[8];

    const int B  = in_sizes[0] / 4;
    const int SF = in_sizes[3] / B;
    const int N  = in_sizes[4] / 3;

    float inv_cnt = (float)(1.0 / (3.0 * (double)B));
    float* outp = (float*)d_out;

    const int nseg = B / ELEMS_PER_BLOCK;

    // workspace layout: pairs | dirs | partials | w4 (256-aligned)
    size_t off_pairs = 0;
    size_t off_dirs  = off_pairs + (size_t)B * 16;
    size_t off_part  = off_dirs + (size_t)nseg * NBUCKET * 4;
    size_t off_w4    = (off_part + (size_t)nseg * 4 + 255) & ~(size_t)255;
    size_t need      = off_w4 + (size_t)N * 16;

    uvec4* pairs    = (uvec4*)((char*)d_ws + off_pairs);
    int*   dirs     = (int*)((char*)d_ws + off_dirs);
    float* partials = (float*)((char*)d_ws + off_part);
    float* w4       = (float*)((char*)d_ws + off_w4);

    const bool pipe_ok = (B % (ELEMS_PER_BLOCK * 8) == 0) && (ws_size >= need) &&
                         (N > NBUCKET);

    if (pipe_ok) {
        int shift = 0;
        while (((long long)(N - 1) >> shift) >= NBUCKET) ++shift;

        k1_bin_prep<<<nseg + NPREP, NTHREADS, 0, stream>>>(
            quat, tpos, bias, batchX, pos_all, vel_all, grav, indices, seqlen,
            SF, shift, nseg, N, pairs, dirs, w4);
        k2_gather_w<<<nseg, NTHREADS, 0, stream>>>(
            w4, pairs, dirs, partials);
        pos_loss_finish<<<1, NTHREADS, 0, stream>>>(
            partials, nseg, inv_cnt, outp);
    } else {
        float* fpart = (float*)d_ws;
        pos_loss_partial<<<NBLOCKS, NTHREADS, 0, stream>>>(
            quat, tpos, bias, batchX, pos_all, vel_all, grav, indices, seqlen,
            B, SF, fpart);
        pos_loss_finish<<<1, NTHREADS, 0, stream>>>(
            fpart, NBLOCKS, inv_cnt, outp);
    }
}

// Round 14
// 60.979 us; speedup vs baseline: 1.0925x; 1.0925x over previous
//
#include <hip/hip_runtime.h>
#include <math.h>

#define DT 0.005f
#define NTHREADS 256
#define NBLOCKS 2048
#define NBUCKET 32
#define ELEMS_PER_BLOCK 1024
#define ROUNDS 4

typedef float    fvec4 __attribute__((ext_vector_type(4)));
typedef float    fvec2 __attribute__((ext_vector_type(2)));
typedef int      ivec4 __attribute__((ext_vector_type(4)));
typedef unsigned uvec4 __attribute__((ext_vector_type(4)));

__device__ __forceinline__ fvec4 ntload4f(const float* p) {
    return __builtin_nontemporal_load(reinterpret_cast<const fvec4*>(p));
}
__device__ __forceinline__ fvec2 ntload2f(const float* p) {
    return __builtin_nontemporal_load(reinterpret_cast<const fvec2*>(p));
}
__device__ __forceinline__ float ntloadf(const float* p) {
    return __builtin_nontemporal_load(p);
}
__device__ __forceinline__ int ntloadi(const int* p) {
    return __builtin_nontemporal_load(p);
}
__device__ __forceinline__ ivec4 ntload4i(const int* p) {
    return __builtin_nontemporal_load(reinterpret_cast<const ivec4*>(p));
}
__device__ __forceinline__ uvec4 ntload4u(const unsigned* p) {
    return __builtin_nontemporal_load(reinterpret_cast<const uvec4*>(p));
}

__device__ __forceinline__ float huber3(float dx, float dy, float dz) {
    float adx = fabsf(dx), ady = fabsf(dy), adz = fabsf(dz);
    float h = (adx < 1.f) ? 0.5f * dx * dx : adx - 0.5f;
    h += (ady < 1.f) ? 0.5f * dy * dy : ady - 0.5f;
    h += (adz < 1.f) ? 0.5f * dz * dz : adz - 0.5f;
    return h;
}

// quat-rotate + combine, inputs already in registers
__device__ __forceinline__ void rot_combine(
    fvec4 q, float ax, float ay, float az,
    float tpx, float tpy, float tpz,
    float gx, float gy, float gz, float half_dt2,
    float& cx, float& cy, float& cz)
{
    float t0 = -(q.y * ax + q.z * ay + q.w * az);
    float t1 =   q.x * ax + q.z * az - q.w * ay;
    float t2 =   q.x * ay - q.y * az + q.w * ax;
    float t3 =   q.x * az + q.y * ay - q.z * ax;
    float rx = -t0 * q.y + t1 * q.x - t2 * q.w + t3 * q.z;
    float ry = -t0 * q.z + t1 * q.w + t2 * q.x - t3 * q.y;
    float rz = -t0 * q.w - t1 * q.z + t2 * q.y + t3 * q.x;

    cx = half_dt2 * (gx + rx) - tpx;
    cy = half_dt2 * (gy + ry) - tpy;
    cz = half_dt2 * (gz + rz) - tpz;
}

// ---------------- K1: 4 consecutive elems/thread, fully vectorized dense loads ----------------
__global__ __launch_bounds__(NTHREADS) void k1_bin(
    const float* __restrict__ quat,
    const float* __restrict__ tpos,
    const float* __restrict__ bias,
    const float* __restrict__ batchX,
    const float* __restrict__ grav,
    const int*   __restrict__ indices,
    const int*   __restrict__ seq_len_p,
    int SF, int shift,
    uvec4* __restrict__ pairs,      // B entries, block-contiguous bucket-sorted
    int*   __restrict__ dirs)       // nseg*NBUCKET counts
{
    const int S = *seq_len_p;
    const int F = SF / S;
    const int last_off = (S - 1) * F;
    const float gx = grav[0], gy = grav[1], gz = grav[2];
    const float half_dt2 = 0.5f * DT * DT;

    __shared__ int   cnt[ROUNDS][4][NBUCKET];
    __shared__ int   offarr[ROUNDS][4][NBUCKET];
    __shared__ int   bstart[NBUCKET];
    __shared__ uvec4 stage[ELEMS_PER_BLOCK];

    const int tid  = threadIdx.x;
    const int wave = tid >> 6;
    const int lane = tid & 63;
    const unsigned long long ltmask = (1ull << lane) - 1ull;

    for (int k = tid; k < ROUNDS * 4 * NBUCKET; k += NTHREADS)
        ((int*)cnt)[k] = 0;
    __syncthreads();

    const int base = blockIdx.x * ELEMS_PER_BLOCK;
    const int i0   = base + tid * 4;          // this thread's 4 consecutive elements

    // ---- vectorized dense loads (all 16B, aligned) ----
    ivec4 iv = ntload4i(indices + i0);

    fvec4 q[4];
    #pragma unroll
    for (int r = 0; r < 4; ++r)
        q[r] = ntload4f(quat + (size_t)(i0 + r) * 4);

    float tpf[12], bpf[12];
    {
        fvec4 a = ntload4f(tpos + (size_t)i0 * 3);
        fvec4 b = ntload4f(tpos + (size_t)i0 * 3 + 4);
        fvec4 c = ntload4f(tpos + (size_t)i0 * 3 + 8);
        *reinterpret_cast<fvec4*>(&tpf[0]) = a;
        *reinterpret_cast<fvec4*>(&tpf[4]) = b;
        *reinterpret_cast<fvec4*>(&tpf[8]) = c;
        fvec4 d = ntload4f(bias + (size_t)i0 * 3);
        fvec4 e = ntload4f(bias + (size_t)i0 * 3 + 4);
        fvec4 f = ntload4f(bias + (size_t)i0 * 3 + 8);
        *reinterpret_cast<fvec4*>(&bpf[0]) = d;
        *reinterpret_cast<fvec4*>(&bpf[4]) = e;
        *reinterpret_cast<fvec4*>(&bpf[8]) = f;
    }

    float axr[4], ayr[4], azr[4];
    #pragma unroll
    for (int r = 0; r < 4; ++r) {
        const float* xb = batchX + (size_t)(i0 + r) * SF + last_off;
        fvec2 a01 = ntload2f(xb);
        axr[r] = a01.x;
        ayr[r] = a01.y;
        azr[r] = ntloadf(xb + 2);
    }

    // ---- binning (round r = element i0+r) + compute ----
    int   idxv[ROUNDS], bckt[ROUNDS], rnk[ROUNDS];
    float cxv[ROUNDS], cyv[ROUNDS], czv[ROUNDS];
    int ivarr[4] = {iv.x, iv.y, iv.z, iv.w};

    #pragma unroll
    for (int r = 0; r < ROUNDS; ++r) {
        int idx = ivarr[r] - (S - 1);
        if (idx < 0) idx = 0;
        idxv[r] = idx;
        int b = idx >> shift; if (b > NBUCKET - 1) b = NBUCKET - 1;
        bckt[r] = b;

        unsigned long long mask = ~0ull;
        #pragma unroll
        for (int k = 0; k < 5; ++k) {
            unsigned long long bm = __ballot((b >> k) & 1);
            mask &= ((b >> k) & 1) ? bm : ~bm;
        }
        rnk[r] = __popcll(mask & ltmask);
        if (rnk[r] == 0) cnt[r][wave][b] = __popcll(mask);

        rot_combine(q[r], axr[r] - bpf[3 * r + 0], ayr[r] - bpf[3 * r + 1],
                    azr[r] - bpf[3 * r + 2],
                    tpf[3 * r + 0], tpf[3 * r + 1], tpf[3 * r + 2],
                    gx, gy, gz, half_dt2, cxv[r], cyv[r], czv[r]);
    }
    __syncthreads();

    // deterministic per-bucket scan over (round, wave) in fixed order
    if (tid < NBUCKET) {
        int b = tid, off = 0;
        #pragma unroll
        for (int r = 0; r < ROUNDS; ++r)
            #pragma unroll
            for (int w = 0; w < 4; ++w) {
                offarr[r][w][b] = off;
                off += cnt[r][w][b];
            }
        dirs[blockIdx.x * NBUCKET + b] = off;
        cnt[0][0][b] = off;   // totals
    }
    __syncthreads();
    if (tid == 0) {
        int s = 0;
        #pragma unroll
        for (int b = 0; b < NBUCKET; ++b) { bstart[b] = s; s += cnt[0][0][b]; }
    }
    __syncthreads();

    #pragma unroll
    for (int r = 0; r < ROUNDS; ++r) {
        int slot = bstart[bckt[r]] + offarr[r][wave][bckt[r]] + rnk[r];
        uvec4 v;
        v.x = (unsigned)idxv[r];
        v.y = __float_as_uint(cxv[r]);
        v.z = __float_as_uint(cyv[r]);
        v.w = __float_as_uint(czv[r]);
        stage[slot] = v;
    }
    __syncthreads();

    #pragma unroll
    for (int r = 0; r < ROUNDS; ++r)
        pairs[(size_t)base + r * NTHREADS + tid] = stage[r * NTHREADS + tid];
}

// ---------------- K2: XCD-sliced gather (round-12 proven) ----------------
__global__ __launch_bounds__(NTHREADS) void k2_gather(
    const float* __restrict__ pos_all,
    const float* __restrict__ vel_all,
    const uvec4* __restrict__ pairs,
    const int*   __restrict__ dirs,
    float* __restrict__ partials)
{
    const int r = blockIdx.x & 7;
    const int j = blockIdx.x >> 3;
    const int tid = threadIdx.x;

    __shared__ int dcnt[8][NBUCKET];
    __shared__ int segSrc[8];
    __shared__ int segCum[9];
    __shared__ float wsum[NTHREADS / 64];

    {
        int s = tid >> 5, bb = tid & (NBUCKET - 1);
        dcnt[s][bb] = dirs[(j * 8 + s) * NBUCKET + bb];
    }
    __syncthreads();

    float hsum = 0.f;

    for (int phase = 0; phase < NBUCKET / 8; ++phase) {
        const int b = r + 8 * phase;

        if (tid < 8) {
            int s = tid, st = 0;
            for (int bb = 0; bb < b; ++bb) st += dcnt[s][bb];
            segSrc[s] = (j * 8 + s) * ELEMS_PER_BLOCK + st;
            segCum[s] = dcnt[s][b];
        }
        __syncthreads();
        if (tid == 0) {
            int c = 0;
            #pragma unroll
            for (int s = 0; s < 8; ++s) { int l = segCum[s]; segCum[s] = c; c += l; }
            segCum[8] = c;
        }
        __syncthreads();

        const int tot = segCum[8];
        for (int m = tid; m < tot; m += NTHREADS) {
            int s = 0;
            #pragma unroll
            for (int k = 1; k < 8; ++k) s += (m >= segCum[k]);
            uvec4 pr = ntload4u(
                reinterpret_cast<const unsigned*>(pairs + segSrc[s] + (m - segCum[s])));
            int idx = (int)pr.x;
            const float* pp = pos_all + (size_t)idx * 3;
            const float* vp = vel_all + (size_t)idx * 3;
            hsum += huber3(pp[0] + vp[0] * DT + __uint_as_float(pr.y),
                           pp[1] + vp[1] * DT + __uint_as_float(pr.z),
                           pp[2] + vp[2] * DT + __uint_as_float(pr.w));
        }
        __syncthreads();
    }

    for (int off = 32; off > 0; off >>= 1)
        hsum += __shfl_down(hsum, off);

    int lane = tid & 63, wid = tid >> 6;
    if (lane == 0) wsum[wid] = hsum;
    __syncthreads();
    if (tid == 0) {
        float s = 0.f;
        for (int w = 0; w < NTHREADS / 64; ++w) s += wsum[w];
        partials[blockIdx.x] = s;
    }
}

// ---------------- Fallback: proven round-5 single-pass ----------------
__global__ __launch_bounds__(NTHREADS) void pos_loss_partial(
    const float* __restrict__ quat,
    const float* __restrict__ tpos,
    const float* __restrict__ bias,
    const float* __restrict__ batchX,
    const float* __restrict__ pos_all,
    const float* __restrict__ vel_all,
    const float* __restrict__ grav,
    const int*   __restrict__ indices,
    const int*   __restrict__ seq_len_p,
    int B, int SF,
    float* __restrict__ partials)
{
    const int S = *seq_len_p;
    const int F = SF / S;
    const int last_off = (S - 1) * F;
    const float gx = grav[0], gy = grav[1], gz = grav[2];
    const float half_dt2 = 0.5f * DT * DT;

    float hsum = 0.f;

    for (int i = blockIdx.x * blockDim.x + threadIdx.x; i < B;
         i += gridDim.x * blockDim.x) {
        int idx = ntloadi(indices + i) - (S - 1);
        if (idx < 0) idx = 0;
        const float* pp = pos_all + (size_t)idx * 3;
        const float* vp = vel_all + (size_t)idx * 3;
        float p0x = pp[0], p0y = pp[1], p0z = pp[2];
        float v0x = vp[0], v0y = vp[1], v0z = vp[2];

        fvec4 q = ntload4f(quat + (size_t)i * 4);
        const float* tp = tpos + (size_t)i * 3;
        float tpx = ntloadf(tp + 0), tpy = ntloadf(tp + 1), tpz = ntloadf(tp + 2);
        const float* bp = bias + (size_t)i * 3;
        float bx = ntloadf(bp + 0), by = ntloadf(bp + 1), bz = ntloadf(bp + 2);
        const float* xb = batchX + (size_t)i * SF + last_off;
        float cx, cy, cz;
        rot_combine(q, ntloadf(xb + 0) - bx, ntloadf(xb + 1) - by,
                    ntloadf(xb + 2) - bz, tpx, tpy, tpz,
                    gx, gy, gz, half_dt2, cx, cy, cz);

        hsum += huber3(p0x + v0x * DT + cx,
                       p0y + v0y * DT + cy,
                       p0z + v0z * DT + cz);
    }

    for (int off = 32; off > 0; off >>= 1)
        hsum += __shfl_down(hsum, off);

    __shared__ float wsum[NTHREADS / 64];
    int lane = threadIdx.x & 63;
    int wid  = threadIdx.x >> 6;
    if (lane == 0) wsum[wid] = hsum;
    __syncthreads();
    if (threadIdx.x == 0) {
        float s = 0.f;
        for (int w = 0; w < NTHREADS / 64; ++w) s += wsum[w];
        partials[blockIdx.x] = s;
    }
}

__global__ __launch_bounds__(NTHREADS) void pos_loss_finish(
    const float* __restrict__ partials, int nb, float inv_cnt,
    float* __restrict__ out)
{
    float s = 0.f;
    for (int i = threadIdx.x; i < nb; i += NTHREADS) s += partials[i];
    for (int off = 32; off > 0; off >>= 1)
        s += __shfl_down(s, off);
    __shared__ float wsum[NTHREADS / 64];
    int lane = threadIdx.x & 63;
    int wid  = threadIdx.x >> 6;
    if (lane == 0) wsum[wid] = s;
    __syncthreads();
    if (threadIdx.x == 0) {
        float tot = 0.f;
        for (int w = 0; w < NTHREADS / 64; ++w) tot += wsum[w];
        out[0] = tot * inv_cnt;
    }
}

extern "C" void kernel_launch(void* const* d_in, const int* in_sizes, int n_in,
                              void* d_out, int out_size, void* d_ws, size_t ws_size,
                              hipStream_t stream) {
    const float* quat    = (const float*)d_in[0];
    const float* tpos    = (const float*)d_in[1];
    const float* bias    = (const float*)d_in[2];
    const float* batchX  = (const float*)d_in[3];
    const float* pos_all = (const float*)d_in[4];
    const float* vel_all = (const float*)d_in[5];
    const float* grav    = (const float*)d_in[6];
    const int*   indices = (const int*)d_in[7];
    const int*   seqlen  = (const int*)d_in[8];

    const int B  = in_sizes[0] / 4;
    const int SF = in_sizes[3] / B;
    const int N  = in_sizes[4] / 3;

    float inv_cnt = (float)(1.0 / (3.0 * (double)B));
    float* outp = (float*)d_out;

    const int nseg = B / ELEMS_PER_BLOCK;
    uvec4* pairs    = (uvec4*)d_ws;
    int*   dirs     = (int*)((char*)d_ws + (size_t)B * 16);
    float* partials = (float*)((char*)d_ws + (size_t)B * 16 +
                               (size_t)nseg * NBUCKET * 4);
    const size_t need = (size_t)B * 16 + (size_t)nseg * NBUCKET * 4 +
                        (size_t)nseg * 4 + 256;

    const bool pipe_ok = (B % (ELEMS_PER_BLOCK * 8) == 0) && (ws_size >= need) &&
                         (N > NBUCKET);

    if (pipe_ok) {
        int shift = 0;
        while (((long long)(N - 1) >> shift) >= NBUCKET) ++shift;

        k1_bin<<<nseg, NTHREADS, 0, stream>>>(
            quat, tpos, bias, batchX, grav, indices, seqlen,
            SF, shift, pairs, dirs);
        k2_gather<<<nseg, NTHREADS, 0, stream>>>(
            pos_all, vel_all, pairs, dirs, partials);
        pos_loss_finish<<<1, NTHREADS, 0, stream>>>(
            partials, nseg, inv_cnt, outp);
    } else {
        float* fpart = (float*)d_ws;
        pos_loss_partial<<<NBLOCKS, NTHREADS, 0, stream>>>(
            quat, tpos, bias, batchX, pos_all, vel_all, grav, indices, seqlen,
            B, SF, fpart);
        pos_loss_finish<<<1, NTHREADS, 0, stream>>>(
            fpart, NBLOCKS, inv_cnt, outp);
    }
}

// Round 15
// 59.727 us; speedup vs baseline: 1.1153x; 1.0210x over previous
//
#include <hip/hip_runtime.h>
#include <math.h>

#define DT 0.005f
#define NTHREADS 256
#define NBLOCKS 2048
#define NBUCKET 32
#define ELEMS_PER_BLOCK 1024
#define ROUNDS 4

typedef float    fvec4 __attribute__((ext_vector_type(4)));
typedef float    fvec2 __attribute__((ext_vector_type(2)));
typedef unsigned uvec4 __attribute__((ext_vector_type(4)));
// 4-byte-aligned 16B vector for the 12B-stride gather
typedef float    fvec4u __attribute__((ext_vector_type(4), aligned(4)));

__device__ __forceinline__ fvec4 ntload4f(const float* p) {
    return __builtin_nontemporal_load(reinterpret_cast<const fvec4*>(p));
}
__device__ __forceinline__ fvec2 ntload2f(const float* p) {
    return __builtin_nontemporal_load(reinterpret_cast<const fvec2*>(p));
}
__device__ __forceinline__ float ntloadf(const float* p) {
    return __builtin_nontemporal_load(p);
}
__device__ __forceinline__ int ntloadi(const int* p) {
    return __builtin_nontemporal_load(p);
}
__device__ __forceinline__ uvec4 ntload4u(const unsigned* p) {
    return __builtin_nontemporal_load(reinterpret_cast<const uvec4*>(p));
}

__device__ __forceinline__ void stream_compute(
    const float* __restrict__ quat, const float* __restrict__ tpos,
    const float* __restrict__ bias, const float* __restrict__ batchX,
    int i, int SF, int last_off,
    float gx, float gy, float gz, float half_dt2,
    float& cx, float& cy, float& cz)
{
    fvec4 q = ntload4f(quat + (size_t)i * 4);
    const float* tp = tpos + (size_t)i * 3;
    float tpx = ntloadf(tp + 0), tpy = ntloadf(tp + 1), tpz = ntloadf(tp + 2);
    const float* bp = bias + (size_t)i * 3;
    float bx = ntloadf(bp + 0), by = ntloadf(bp + 1), bz = ntloadf(bp + 2);
    const float* xb = batchX + (size_t)i * SF + last_off;
    fvec2 a01 = ntload2f(xb);
    float ax = a01.x - bx;
    float ay = a01.y - by;
    float az = ntloadf(xb + 2) - bz;

    float t0 = -(q.y * ax + q.z * ay + q.w * az);
    float t1 =   q.x * ax + q.z * az - q.w * ay;
    float t2 =   q.x * ay - q.y * az + q.w * ax;
    float t3 =   q.x * az + q.y * ay - q.z * ax;
    float rx = -t0 * q.y + t1 * q.x - t2 * q.w + t3 * q.z;
    float ry = -t0 * q.z + t1 * q.w + t2 * q.x - t3 * q.y;
    float rz = -t0 * q.w - t1 * q.z + t2 * q.y + t3 * q.x;

    cx = half_dt2 * (gx + rx) - tpx;
    cy = half_dt2 * (gy + ry) - tpy;
    cz = half_dt2 * (gz + rz) - tpz;
}

__device__ __forceinline__ float huber3(float dx, float dy, float dz) {
    float adx = fabsf(dx), ady = fabsf(dy), adz = fabsf(dz);
    float h = (adx < 1.f) ? 0.5f * dx * dx : adx - 0.5f;
    h += (ady < 1.f) ? 0.5f * dy * dy : ady - 0.5f;
    h += (adz < 1.f) ? 0.5f * dz * dz : adz - 0.5f;
    return h;
}

// ---------------- K1: stream + deterministic 32-bucket multisplit (round-12 proven) ----------------
__global__ __launch_bounds__(NTHREADS) void k1_bin(
    const float* __restrict__ quat,
    const float* __restrict__ tpos,
    const float* __restrict__ bias,
    const float* __restrict__ batchX,
    const float* __restrict__ grav,
    const int*   __restrict__ indices,
    const int*   __restrict__ seq_len_p,
    int SF, int shift,
    uvec4* __restrict__ pairs,
    int*   __restrict__ dirs)
{
    const int S = *seq_len_p;
    const int F = SF / S;
    const int last_off = (S - 1) * F;
    const float gx = grav[0], gy = grav[1], gz = grav[2];
    const float half_dt2 = 0.5f * DT * DT;

    __shared__ int   cnt[ROUNDS][4][NBUCKET];
    __shared__ int   offarr[ROUNDS][4][NBUCKET];
    __shared__ int   bstart[NBUCKET];
    __shared__ uvec4 stage[ELEMS_PER_BLOCK];

    const int tid  = threadIdx.x;
    const int wave = tid >> 6;
    const int lane = tid & 63;
    const unsigned long long ltmask = (1ull << lane) - 1ull;

    for (int k = tid; k < ROUNDS * 4 * NBUCKET; k += NTHREADS)
        ((int*)cnt)[k] = 0;
    __syncthreads();

    const int base = blockIdx.x * ELEMS_PER_BLOCK;

    int   idxv[ROUNDS], bckt[ROUNDS], rnk[ROUNDS];
    float cxv[ROUNDS], cyv[ROUNDS], czv[ROUNDS];

    #pragma unroll
    for (int r = 0; r < ROUNDS; ++r) {
        const int i = base + r * NTHREADS + tid;
        int idx = ntloadi(indices + i) - (S - 1);
        if (idx < 0) idx = 0;
        idxv[r] = idx;
        int b = idx >> shift; if (b > NBUCKET - 1) b = NBUCKET - 1;
        bckt[r] = b;

        unsigned long long mask = ~0ull;
        #pragma unroll
        for (int k = 0; k < 5; ++k) {
            unsigned long long bm = __ballot((b >> k) & 1);
            mask &= ((b >> k) & 1) ? bm : ~bm;
        }
        rnk[r] = __popcll(mask & ltmask);
        if (rnk[r] == 0) cnt[r][wave][b] = __popcll(mask);

        stream_compute(quat, tpos, bias, batchX, i, SF, last_off,
                       gx, gy, gz, half_dt2, cxv[r], cyv[r], czv[r]);
    }
    __syncthreads();

    if (tid < NBUCKET) {
        int b = tid, off = 0;
        #pragma unroll
        for (int r = 0; r < ROUNDS; ++r)
            #pragma unroll
            for (int w = 0; w < 4; ++w) {
                offarr[r][w][b] = off;
                off += cnt[r][w][b];
            }
        dirs[blockIdx.x * NBUCKET + b] = off;
        cnt[0][0][b] = off;
    }
    __syncthreads();
    if (tid == 0) {
        int s = 0;
        #pragma unroll
        for (int b = 0; b < NBUCKET; ++b) { bstart[b] = s; s += cnt[0][0][b]; }
    }
    __syncthreads();

    #pragma unroll
    for (int r = 0; r < ROUNDS; ++r) {
        int slot = bstart[bckt[r]] + offarr[r][wave][bckt[r]] + rnk[r];
        uvec4 v;
        v.x = (unsigned)idxv[r];
        v.y = __float_as_uint(cxv[r]);
        v.z = __float_as_uint(cyv[r]);
        v.w = __float_as_uint(czv[r]);
        stage[slot] = v;
    }
    __syncthreads();

    #pragma unroll
    for (int r = 0; r < ROUNDS; ++r)
        pairs[(size_t)base + r * NTHREADS + tid] = stage[r * NTHREADS + tid];
}

// ---------------- K2: XCD-sliced gather, vector pos/vel loads ----------------
__global__ __launch_bounds__(NTHREADS) void k2_gather(
    const float* __restrict__ pos_all,
    const float* __restrict__ vel_all,
    const uvec4* __restrict__ pairs,
    const int*   __restrict__ dirs,
    int Nm1,
    float* __restrict__ partials)
{
    const int r = blockIdx.x & 7;
    const int j = blockIdx.x >> 3;
    const int tid = threadIdx.x;

    __shared__ int dcnt[8][NBUCKET];
    __shared__ int segSrc[8];
    __shared__ int segCum[9];
    __shared__ float wsum[NTHREADS / 64];

    {
        int s = tid >> 5, bb = tid & (NBUCKET - 1);
        dcnt[s][bb] = dirs[(j * 8 + s) * NBUCKET + bb];
    }
    __syncthreads();

    float hsum = 0.f;

    for (int phase = 0; phase < NBUCKET / 8; ++phase) {
        const int b = r + 8 * phase;

        if (tid < 8) {
            int s = tid, st = 0;
            for (int bb = 0; bb < b; ++bb) st += dcnt[s][bb];
            segSrc[s] = (j * 8 + s) * ELEMS_PER_BLOCK + st;
            segCum[s] = dcnt[s][b];
        }
        __syncthreads();
        if (tid == 0) {
            int c = 0;
            #pragma unroll
            for (int s = 0; s < 8; ++s) { int l = segCum[s]; segCum[s] = c; c += l; }
            segCum[8] = c;
        }
        __syncthreads();

        const int tot = segCum[8];
        for (int m = tid; m < tot; m += NTHREADS) {
            int s = 0;
            #pragma unroll
            for (int k = 1; k < 8; ++k) s += (m >= segCum[k]);
            uvec4 pr = ntload4u(
                reinterpret_cast<const unsigned*>(pairs + segSrc[s] + (m - segCum[s])));
            int idx = (int)pr.x;

            float px, py, pz, vx, vy, vz;
            if (idx < Nm1) {
                // one 16B load per array (4B-aligned dwordx4; last lane unused)
                fvec4u pv = *reinterpret_cast<const fvec4u*>(pos_all + (size_t)idx * 3);
                fvec4u vv = *reinterpret_cast<const fvec4u*>(vel_all + (size_t)idx * 3);
                px = pv.x; py = pv.y; pz = pv.z;
                vx = vv.x; vy = vv.y; vz = vv.z;
            } else {
                const float* pp = pos_all + (size_t)idx * 3;
                const float* vp = vel_all + (size_t)idx * 3;
                px = pp[0]; py = pp[1]; pz = pp[2];
                vx = vp[0]; vy = vp[1]; vz = vp[2];
            }

            hsum += huber3(px + vx * DT + __uint_as_float(pr.y),
                           py + vy * DT + __uint_as_float(pr.z),
                           pz + vz * DT + __uint_as_float(pr.w));
        }
        __syncthreads();
    }

    for (int off = 32; off > 0; off >>= 1)
        hsum += __shfl_down(hsum, off);

    int lane = tid & 63, wid = tid >> 6;
    if (lane == 0) wsum[wid] = hsum;
    __syncthreads();
    if (tid == 0) {
        float s = 0.f;
        for (int w = 0; w < NTHREADS / 64; ++w) s += wsum[w];
        partials[blockIdx.x] = s;
    }
}

// ---------------- Fallback: proven round-5 single-pass ----------------
__global__ __launch_bounds__(NTHREADS) void pos_loss_partial(
    const float* __restrict__ quat,
    const float* __restrict__ tpos,
    const float* __restrict__ bias,
    const float* __restrict__ batchX,
    const float* __restrict__ pos_all,
    const float* __restrict__ vel_all,
    const float* __restrict__ grav,
    const int*   __restrict__ indices,
    const int*   __restrict__ seq_len_p,
    int B, int SF,
    float* __restrict__ partials)
{
    const int S = *seq_len_p;
    const int F = SF / S;
    const int last_off = (S - 1) * F;
    const float gx = grav[0], gy = grav[1], gz = grav[2];
    const float half_dt2 = 0.5f * DT * DT;

    float hsum = 0.f;

    for (int i = blockIdx.x * blockDim.x + threadIdx.x; i < B;
         i += gridDim.x * blockDim.x) {
        int idx = ntloadi(indices + i) - (S - 1);
        if (idx < 0) idx = 0;
        const float* pp = pos_all + (size_t)idx * 3;
        const float* vp = vel_all + (size_t)idx * 3;
        float p0x = pp[0], p0y = pp[1], p0z = pp[2];
        float v0x = vp[0], v0y = vp[1], v0z = vp[2];

        float cx, cy, cz;
        stream_compute(quat, tpos, bias, batchX, i, SF, last_off,
                       gx, gy, gz, half_dt2, cx, cy, cz);

        hsum += huber3(p0x + v0x * DT + cx,
                       p0y + v0y * DT + cy,
                       p0z + v0z * DT + cz);
    }

    for (int off = 32; off > 0; off >>= 1)
        hsum += __shfl_down(hsum, off);

    __shared__ float wsum[NTHREADS / 64];
    int lane = threadIdx.x & 63;
    int wid  = threadIdx.x >> 6;
    if (lane == 0) wsum[wid] = hsum;
    __syncthreads();
    if (threadIdx.x == 0) {
        float s = 0.f;
        for (int w = 0; w < NTHREADS / 64; ++w) s += wsum[w];
        partials[blockIdx.x] = s;
    }
}

__global__ __launch_bounds__(NTHREADS) void pos_loss_finish(
    const float* __restrict__ partials, int nb, float inv_cnt,
    float* __restrict__ out)
{
    float s = 0.f;
    for (int i = threadIdx.x; i < nb; i += NTHREADS) s += partials[i];
    for (int off = 32; off > 0; off >>= 1)
        s += __shfl_down(s, off);
    __shared__ float wsum[NTHREADS / 64];
    int lane = threadIdx.x & 63;
    int wid  = threadIdx.x >> 6;
    if (lane == 0) wsum[wid] = s;
    __syncthreads();
    if (threadIdx.x == 0) {
        float tot = 0.f;
        for (int w = 0; w < NTHREADS / 64; ++w) tot += wsum[w];
        out[0] = tot * inv_cnt;
    }
}

extern "C" void kernel_launch(void* const* d_in, const int* in_sizes, int n_in,
                              void* d_out, int out_size, void* d_ws, size_t ws_size,
                              hipStream_t stream) {
    const float* quat    = (const float*)d_in[0];
    const float* tpos    = (const float*)d_in[1];
    const float* bias    = (const float*)d_in[2];
    const float* batchX  = (const float*)d_in[3];
    const float* pos_all = (const float*)d_in[4];
    const float* vel_all = (const float*)d_in[5];
    const float* grav    = (const float*)d_in[6];
    const int*   indices = (const int*)d_in[7];
    const int*   seqlen  = (const int*)d_in[8];

    const int B  = in_sizes[0] / 4;
    const int SF = in_sizes[3] / B;
    const int N  = in_sizes[4] / 3;

    float inv_cnt = (float)(1.0 / (3.0 * (double)B));
    float* outp = (float*)d_out;

    const int nseg = B / ELEMS_PER_BLOCK;
    uvec4* pairs    = (uvec4*)d_ws;
    int*   dirs     = (int*)((char*)d_ws + (size_t)B * 16);
    float* partials = (float*)((char*)d_ws + (size_t)B * 16 +
                               (size_t)nseg * NBUCKET * 4);
    const size_t need = (size_t)B * 16 + (size_t)nseg * NBUCKET * 4 +
                        (size_t)nseg * 4 + 256;

    const bool pipe_ok = (B % (ELEMS_PER_BLOCK * 8) == 0) && (ws_size >= need) &&
                         (N > NBUCKET);

    if (pipe_ok) {
        int shift = 0;
        while (((long long)(N - 1) >> shift) >= NBUCKET) ++shift;

        k1_bin<<<nseg, NTHREADS, 0, stream>>>(
            quat, tpos, bias, batchX, grav, indices, seqlen,
            SF, shift, pairs, dirs);
        k2_gather<<<nseg, NTHREADS, 0, stream>>>(
            pos_all, vel_all, pairs, dirs, N - 1, partials);
        pos_loss_finish<<<1, NTHREADS, 0, stream>>>(
            partials, nseg, inv_cnt, outp);
    } else {
        float* fpart = (float*)d_ws;
        pos_loss_partial<<<NBLOCKS, NTHREADS, 0, stream>>>(
            quat, tpos, bias, batchX, pos_all, vel_all, grav, indices, seqlen,
            B, SF, fpart);
        pos_loss_finish<<<1, NTHREADS, 0, stream>>>(
            fpart, NBLOCKS, inv_cnt, outp);
    }
}